// Round 10
// baseline (294.696 us; speedup 1.0000x reference)
//
#include <hip/hip_runtime.h>

// ---- problem constants ----
#define TT 100
#define BB 1024
#define NI 256
#define NH 512
#define NO 10
#define TB (TT*BB)            // 102400 rows
#define GK 512                 // doubled K (hi/lo interleave)
#define GN 512

// output layout (floats), return order: cur1, cur2, spk1, spk2, mem1, mem2
constexpr long long C1_OFF = 0;
constexpr long long C2_OFF = 52428800LL;            // + T*B*NH
constexpr long long S1_OFF = 53452800LL;            // + T*B*NO
constexpr long long S2_OFF = 105881600LL;
constexpr long long M1_OFF = 106905600LL;
constexpr long long M2_OFF = 159334400LL;

typedef short bf16x8 __attribute__((ext_vector_type(8)));
typedef float f32x4 __attribute__((ext_vector_type(4)));

// round-to-nearest-even f32 -> bf16 bits
__device__ __forceinline__ unsigned int rne_bf16(float f) {
    unsigned int u = __float_as_uint(f);
    return (u + 0x7fffu + ((u >> 16) & 1u)) >> 16;
}

// f32 -> packed [hi,lo] bf16 pair (Dekker split), bit-identical to prior rounds
__device__ __forceinline__ unsigned int pack_hilo(float f) {
    unsigned int hi = rne_bf16(f);
    float hif = __uint_as_float(hi << 16);
    float e = f - hif;
    unsigned int lo = rne_bf16(e);
    return (hi & 0xffffu) | (lo << 16);
}

__device__ __forceinline__ void pack4(uint4& d, const float4& a) {
    d.x = pack_hilo(a.x); d.y = pack_hilo(a.y); d.z = pack_hilo(a.z); d.w = pack_hilo(a.w);
}

// LDS-only barrier (R5-proven correct): orders ds traffic without draining the
// global store/load streams (__syncthreads would emit s_waitcnt vmcnt(0) and
// flush the register prefetch pipeline at every K-iter).
__device__ __forceinline__ void barrier_lds() {
    asm volatile("s_waitcnt lgkmcnt(0)" ::: "memory");
    __builtin_amdgcn_s_barrier();
}

// ---- prep: W1 (f32 {0,0.5}) -> bf16 duplicated pairs, linear [h][gk] (R0-proven) ----
// Wp[h][2k] = Wp[h][2k+1] = bf16(W1[h][k]); pairs match A's hi/lo doubled-k.
__global__ void prep_w_kernel(const float* __restrict__ W1, short* __restrict__ Wp) {
    int i = blockIdx.x * blockDim.x + threadIdx.x;
    if (i >= NH * NI / 4) return;
    float4 v = ((const float4*)W1)[i];
    float f[4] = {v.x, v.y, v.z, v.w};
    uint4 o;
    unsigned int* op = &o.x;
    #pragma unroll
    for (int j = 0; j < 4; ++j) {
        unsigned int hb = __float_as_uint(f[j]) >> 16;   // exact for 0 / 0.5
        op[j] = hb | (hb << 16);
    }
    ((uint4*)Wp)[i] = o;
}

// ---- GEMM1: A via LDS dbuf (R2 path), W via per-wave REGISTER dbuf from
// global (L2-hot), LDS-only barriers. x/W prefetches live across barriers
// in registers -> true pipelining without vmcnt counting or sched pinning.
__launch_bounds__(256, 3)
__global__ void gemm1_kernel(const float* __restrict__ x, const short* __restrict__ Wp,
                             float* __restrict__ C) {
    __shared__ short As[2][128][40];
    const int tid = threadIdx.x;
    const int bid = blockIdx.x;
    const int x8 = bid & 7;
    const int g8 = bid >> 3;
    const int p  = g8 & 3;
    const int panel = (g8 >> 2) * 8 + x8;
    const int m0 = (799 - panel) * 128;    // reversed: high t written first
    const int n0 = p * 128;
    const int wid = tid >> 6;
    const int lane = tid & 63;
    const int wm = (wid >> 1) * 64;
    const int wn = (wid & 1) * 64;

    f32x4 acc[4][4] = {};

    const int srow = tid >> 2;
    const int sc4 = tid & 3;
    const long long ax0 = (long long)(m0 + srow) * NI + sc4 * 4;
    const long long ax1 = ax0 + 64LL * NI;

    const int fr = lane & 15;
    const int fk = (lane >> 4) * 8;        // A frag chunk (shorts)
    const int g  = lane >> 4;              // W frag k-chunk

    // W fragment row bases (shorts): row (n0+wn+i*16+fr), chunk g of tile kt
    // is Wp[row*GK + kt*32 + g*8 .. +8] -- bit-identical to the old LDS path.
    const short* wrow0 = Wp + (long long)(n0 + wn + fr) * GK + g * 8;

    // ---- prologue ----
    bf16x8 wreg[2][4];
    #pragma unroll
    for (int i = 0; i < 4; ++i)
        wreg[0][i] = *(const bf16x8*)(wrow0 + (long long)i * 16 * GK);

    uint4 pa0, pa1;
    {
        float4 t0a = *(const float4*)&x[ax0];
        float4 t0b = *(const float4*)&x[ax1];
        uint4 q0, q1;
        pack4(q0, t0a); pack4(q1, t0b);
        *(uint4*)&As[0][srow][sc4 * 8]      = q0;
        *(uint4*)&As[0][srow + 64][sc4 * 8] = q1;
        float4 t1a = *(const float4*)&x[ax0 + 16];
        float4 t1b = *(const float4*)&x[ax1 + 16];
        pack4(pa0, t1a); pack4(pa1, t1b);
    }
    float4 raw0a = *(const float4*)&x[ax0 + 32];
    float4 raw0b = *(const float4*)&x[ax1 + 32];
    float4 raw1a = *(const float4*)&x[ax0 + 48];
    float4 raw1b = *(const float4*)&x[ax1 + 48];
    barrier_lds();   // As[0] visible; raw/W prefetches stay in flight

    // ---- main loop: 16 K-tiles, LDS-only barrier each ----
    #pragma unroll
    for (int kt = 0; kt < 16; ++kt) {
        const int cur = kt & 1;
        const int nxt = cur ^ 1;

        if (kt + 1 < 16) {
            // W reg prefetch for kt+1 (global, L2-hot; consumed next iter)
            #pragma unroll
            for (int i = 0; i < 4; ++i)
                wreg[nxt][i] = *(const bf16x8*)(wrow0 + (long long)i * 16 * GK + (kt + 1) * 32);
            // A stage for kt+1
            *(uint4*)&As[nxt][srow][sc4 * 8]      = pa0;
            *(uint4*)&As[nxt][srow + 64][sc4 * 8] = pa1;
        }
        if (kt + 2 < 16) {
            if (cur == 0) { pack4(pa0, raw0a); pack4(pa1, raw0b); }
            else          { pack4(pa0, raw1a); pack4(pa1, raw1b); }
        }
        if (kt + 4 < 16) {
            if (cur == 0) {
                raw0a = *(const float4*)&x[ax0 + (long long)(kt + 4) * 16];
                raw0b = *(const float4*)&x[ax1 + (long long)(kt + 4) * 16];
            } else {
                raw1a = *(const float4*)&x[ax0 + (long long)(kt + 4) * 16];
                raw1b = *(const float4*)&x[ax1 + (long long)(kt + 4) * 16];
            }
        }

        bf16x8 af[4];
        #pragma unroll
        for (int i = 0; i < 4; ++i)
            af[i] = *(const bf16x8*)&As[cur][wm + i * 16 + fr][fk];
        #pragma unroll
        for (int i = 0; i < 4; ++i)
            #pragma unroll
            for (int j = 0; j < 4; ++j)
                acc[i][j] = __builtin_amdgcn_mfma_f32_16x16x32_bf16(af[i], wreg[cur][j], acc[i][j], 0, 0, 0);

        if (kt + 1 < 16) barrier_lds();   // As handoff only; prefetches survive
    }

    const int col = lane & 15;
    const int rbase = (lane >> 4) * 4;
    #pragma unroll
    for (int i = 0; i < 4; ++i) {
        #pragma unroll
        for (int j = 0; j < 4; ++j) {
            long long base = (long long)(m0 + wm + i * 16 + rbase) * GN + (n0 + wn + j * 16 + col);
            #pragma unroll
            for (int r = 0; r < 4; ++r)
                C[base + (long long)r * GN] = acc[i][j][r];
        }
    }
}

// ---- fused LIF1 + GEMM2(popcount) + LIF2 (R7-proven, unchanged) ----
__launch_bounds__(512)
__global__ void lif_kernel(const float* __restrict__ cur1, const float* __restrict__ W2,
                           float* __restrict__ out) {
    const int b = blockIdx.x;       // 0..1023
    const int h = threadIdx.x;      // 0..511
    const int w = h >> 6;
    const int lane = h & 63;

    __shared__ unsigned long long wmks[2][2][8];   // [iter parity][t parity][wave]
    __shared__ unsigned long long w2ms[NO][8];

    #pragma unroll
    for (int o = 0; o < NO; ++o) {
        unsigned long long mk = __ballot(W2[o * NH + h] != 0.0f);
        if (lane == 0) w2ms[o][w] = mk;
    }
    __syncthreads();
    unsigned long long w2m[8];
    if (h < NO) {
        #pragma unroll
        for (int i = 0; i < 8; ++i) w2m[i] = w2ms[h][i];
    }

    float m1 = 0.0f, m2 = 0.0f;
    const long long idx1 = (long long)b * NH + h;
    const float* c1p = cur1 + idx1;
    float* s1p = out + S1_OFF + idx1;
    float* m1p = out + M1_OFF + idx1;
    const long long st1 = (long long)BB * NH;   // per-t stride

    float c1a = c1p[0];
    float c1b = c1p[st1];
    for (int t = 0; t < TT; t += 2) {
        const int par = (t >> 1) & 1;

        float c1c = 0.0f, c1d = 0.0f;
        if (t + 2 < TT) c1c = c1p[(long long)(t + 2) * st1];
        if (t + 3 < TT) c1d = c1p[(long long)(t + 3) * st1];

        float rst = (m1 > 1.0f) ? 1.0f : 0.0f;
        m1 = 0.9f * m1 + c1a - rst;
        float s1a = (m1 > 1.0f) ? 1.0f : 0.0f;
        s1p[(long long)t * st1] = s1a;
        m1p[(long long)t * st1] = m1;
        unsigned long long mka = __ballot(s1a != 0.0f);
        if (lane == 0) wmks[par][0][w] = mka;

        float rstb = (m1 > 1.0f) ? 1.0f : 0.0f;
        m1 = 0.9f * m1 + c1b - rstb;
        float s1b = (m1 > 1.0f) ? 1.0f : 0.0f;
        s1p[(long long)(t + 1) * st1] = s1b;
        m1p[(long long)(t + 1) * st1] = m1;
        unsigned long long mkb = __ballot(s1b != 0.0f);
        if (lane == 0) wmks[par][1][w] = mkb;

        barrier_lds();   // orders the wmks ds_writes only; stores stay in flight

        if (h < NO) {
            #pragma unroll
            for (int j = 0; j < 2; ++j) {
                int cnt = 0;
                #pragma unroll
                for (int i = 0; i < 8; ++i) cnt += __popcll(wmks[par][j][i] & w2m[i]);
                float c2 = 0.5f * (float)cnt;    // exact: multiples of 0.5
                float rst2 = (m2 > 1.0f) ? 1.0f : 0.0f;
                m2 = 0.8f * m2 + c2 - rst2;
                float s2 = (m2 > 1.0f) ? 1.0f : 0.0f;
                long long o2 = (long long)(t + j) * (BB * NO) + b * NO + h;
                out[C2_OFF + o2] = c2;
                out[S2_OFF + o2] = s2;
                out[M2_OFF + o2] = m2;
            }
        }
        c1a = c1c; c1b = c1d;
        // no trailing barrier: wmks double-buffered by iteration parity
    }
}

extern "C" void kernel_launch(void* const* d_in, const int* in_sizes, int n_in,
                              void* d_out, int out_size, void* d_ws, size_t ws_size,
                              hipStream_t stream) {
    const float* x  = (const float*)d_in[0];
    const float* W1 = (const float*)d_in[1];
    const float* W2 = (const float*)d_in[2];
    float* out = (float*)d_out;

    // scratch inside d_out: W' (512KB bf16) at start of spk1 region;
    // consumed by gemm1 before lif_kernel overwrites it (stream-ordered).
    short* Wp = (short*)(out + S1_OFF);
    float* C1 = out + C1_OFF;

    prep_w_kernel<<<(NH * NI / 4 + 255) / 256, 256, 0, stream>>>(W1, Wp);
    gemm1_kernel<<<(TB / 128) * (GN / 128), 256, 0, stream>>>(x, Wp, C1);
    lif_kernel<<<BB, NH, 0, stream>>>(C1, W2, out);
}

// Round 11
// 287.976 us; speedup vs baseline: 1.0233x; 1.0233x over previous
//
#include <hip/hip_runtime.h>

// ---- problem constants ----
#define TT 100
#define BB 1024
#define NI 256
#define NH 512
#define NO 10
#define TB (TT*BB)            // 102400 rows
#define GK 512                 // doubled K (hi/lo interleave)
#define GN 512

// output layout (floats), return order: cur1, cur2, spk1, spk2, mem1, mem2
constexpr long long C1_OFF = 0;
constexpr long long C2_OFF = 52428800LL;            // + T*B*NH
constexpr long long S1_OFF = 53452800LL;            // + T*B*NO
constexpr long long S2_OFF = 105881600LL;
constexpr long long M1_OFF = 106905600LL;
constexpr long long M2_OFF = 159334400LL;

typedef short bf16x8 __attribute__((ext_vector_type(8)));
typedef float f32x4 __attribute__((ext_vector_type(4)));

// round-to-nearest-even f32 -> bf16 bits
__device__ __forceinline__ unsigned int rne_bf16(float f) {
    unsigned int u = __float_as_uint(f);
    return (u + 0x7fffu + ((u >> 16) & 1u)) >> 16;
}

// f32 -> packed [hi,lo] bf16 pair (Dekker split), bit-identical to prior rounds
__device__ __forceinline__ unsigned int pack_hilo(float f) {
    unsigned int hi = rne_bf16(f);
    float hif = __uint_as_float(hi << 16);
    float e = f - hif;
    unsigned int lo = rne_bf16(e);
    return (hi & 0xffffu) | (lo << 16);
}

__device__ __forceinline__ void pack4(uint4& d, const float4& a) {
    d.x = pack_hilo(a.x); d.y = pack_hilo(a.y); d.z = pack_hilo(a.z); d.w = pack_hilo(a.w);
}

// W element f32 {0,0.5} -> duplicated bf16 pair (exact)
__device__ __forceinline__ unsigned int dup_w(float f) {
    unsigned int hb = __float_as_uint(f) >> 16;
    return hb | (hb << 16);
}

// LDS-only barrier (R5-proven): orders ds traffic without draining VMEM.
__device__ __forceinline__ void barrier_lds() {
    asm volatile("s_waitcnt lgkmcnt(0)" ::: "memory");
    __builtin_amdgcn_s_barrier();
}

// ---- prep: W1 -> fragment-shuffled image for coalesced wave loads ----
// 16B unit i = (p*16+kt)*512 + rb*64 + l holds, for lane l of frag-row-block rb:
// W row (p*128 + rb*16 + (l&15)), duplicated-pair shorts [kt*32+(l>>4)*8, +8)
// (= W1 floats [kt*16+(l>>4)*4, +4)). A wave frag load = 64 lanes x 16B = 1KB
// CONTIGUOUS -> one perfectly-coalesced global_load_dwordx4 per fragment.
__global__ void prep_w_kernel(const float* __restrict__ W1, short* __restrict__ Wimg) {
    int i = blockIdx.x * blockDim.x + threadIdx.x;
    if (i >= 4 * 16 * 8 * 64) return;              // 32768 units
    int l  = i & 63;
    int rb = (i >> 6) & 7;
    int kt = (i >> 9) & 15;
    int p  = i >> 13;
    int row = p * 128 + rb * 16 + (l & 15);
    int kb  = kt * 16 + (l >> 4) * 4;
    float4 w = *(const float4*)&W1[(long long)row * NI + kb];
    uint4 o;
    o.x = dup_w(w.x); o.y = dup_w(w.y); o.z = dup_w(w.z); o.w = dup_w(w.w);
    ((uint4*)Wimg)[i] = o;
}

// ---- GEMM1: A-panel staged once (2 K-halves), W global->reg dbuf, ----
// ---- barrier-free K-loop (3 barriers/block total).                 ----
__launch_bounds__(256, 2)
__global__ void gemm1_kernel(const float* __restrict__ x, const short* __restrict__ Wimg,
                             float* __restrict__ C) {
    __shared__ short As[128][264];     // 66KB; +8 pad -> conflict-optimal b128 reads
    const int tid = threadIdx.x;
    const int bid = blockIdx.x;
    const int x8 = bid & 7;
    const int g8 = bid >> 3;
    const int p  = g8 & 3;
    const int panel = (g8 >> 2) * 8 + x8;
    const int m0 = (799 - panel) * 128;    // reversed: high t written first
    const int n0 = p * 128;
    const int wid = tid >> 6;
    const int lane = tid & 63;
    const int wm = (wid >> 1) * 64;
    const int wn = (wid & 1) * 64;

    f32x4 acc[4][4] = {};

    const int fr = lane & 15;
    const int fk = (lane >> 4) * 8;        // A frag chunk (shorts)
    const int rb0 = wn >> 4;               // wave's first 16-row block (0 or 4)

    // p-slice of the shuffled W image: 16 kt x 8 rb x 64 lanes x 8 shorts
    const short* wbase = Wimg + (long long)p * 65536;

    // prologue: W frags for kt=0
    bf16x8 wreg[2][4];
    #pragma unroll
    for (int j = 0; j < 4; ++j)
        wreg[0][j] = *(const bf16x8*)(wbase + (0 * 8 + rb0 + j) * 512 + lane * 8);

    #pragma unroll
    for (int half = 0; half < 2; ++half) {
        // ---- stage this K-half of the A panel (coalesced, packed hi/lo) ----
        #pragma unroll
        for (int it = 0; it < 16; ++it) {
            int idx = it * 256 + tid;          // 4096 float4 per half
            int row = idx >> 5, c4 = idx & 31; // 32 float4 per row-half
            float4 a = *(const float4*)&x[(long long)(m0 + row) * NI + half * 128 + c4 * 4];
            uint4 pa; pack4(pa, a);
            *(uint4*)&As[row][c4 * 8] = pa;
        }
        barrier_lds();                         // As visible; W prefetch survives

        // ---- barrier-free K-loop over this half (8 tiles) ----
        #pragma unroll
        for (int ktl = 0; ktl < 8; ++ktl) {
            const int ktg = half * 8 + ktl;
            const int cur = ktg & 1, nxt = cur ^ 1;

            if (ktg + 1 < 16) {
                #pragma unroll
                for (int j = 0; j < 4; ++j)
                    wreg[nxt][j] = *(const bf16x8*)(wbase + ((ktg + 1) * 8 + rb0 + j) * 512 + lane * 8);
            }

            bf16x8 af[4];
            #pragma unroll
            for (int i = 0; i < 4; ++i)
                af[i] = *(const bf16x8*)&As[wm + i * 16 + fr][ktl * 32 + fk];
            #pragma unroll
            for (int i = 0; i < 4; ++i)
                #pragma unroll
                for (int j = 0; j < 4; ++j)
                    acc[i][j] = __builtin_amdgcn_mfma_f32_16x16x32_bf16(af[i], wreg[cur][j], acc[i][j], 0, 0, 0);
        }
        if (half == 0) barrier_lds();          // all reads done before overwrite
    }

    // C/D layout: col = lane&15, row = (lane>>4)*4 + r  (unchanged epilogue)
    const int col = lane & 15;
    const int rbase = (lane >> 4) * 4;
    #pragma unroll
    for (int i = 0; i < 4; ++i) {
        #pragma unroll
        for (int j = 0; j < 4; ++j) {
            long long base = (long long)(m0 + wm + i * 16 + rbase) * GN + (n0 + wn + j * 16 + col);
            #pragma unroll
            for (int r = 0; r < 4; ++r)
                C[base + (long long)r * GN] = acc[i][j][r];
        }
    }
}

// ---- fused LIF1 + GEMM2(popcount) + LIF2 (R7-proven, unchanged) ----
__launch_bounds__(512)
__global__ void lif_kernel(const float* __restrict__ cur1, const float* __restrict__ W2,
                           float* __restrict__ out) {
    const int b = blockIdx.x;       // 0..1023
    const int h = threadIdx.x;      // 0..511
    const int w = h >> 6;
    const int lane = h & 63;

    __shared__ unsigned long long wmks[2][2][8];   // [iter parity][t parity][wave]
    __shared__ unsigned long long w2ms[NO][8];

    #pragma unroll
    for (int o = 0; o < NO; ++o) {
        unsigned long long mk = __ballot(W2[o * NH + h] != 0.0f);
        if (lane == 0) w2ms[o][w] = mk;
    }
    __syncthreads();
    unsigned long long w2m[8];
    if (h < NO) {
        #pragma unroll
        for (int i = 0; i < 8; ++i) w2m[i] = w2ms[h][i];
    }

    float m1 = 0.0f, m2 = 0.0f;
    const long long idx1 = (long long)b * NH + h;
    const float* c1p = cur1 + idx1;
    float* s1p = out + S1_OFF + idx1;
    float* m1p = out + M1_OFF + idx1;
    const long long st1 = (long long)BB * NH;   // per-t stride

    float c1a = c1p[0];
    float c1b = c1p[st1];
    for (int t = 0; t < TT; t += 2) {
        const int par = (t >> 1) & 1;

        float c1c = 0.0f, c1d = 0.0f;
        if (t + 2 < TT) c1c = c1p[(long long)(t + 2) * st1];
        if (t + 3 < TT) c1d = c1p[(long long)(t + 3) * st1];

        float rst = (m1 > 1.0f) ? 1.0f : 0.0f;
        m1 = 0.9f * m1 + c1a - rst;
        float s1a = (m1 > 1.0f) ? 1.0f : 0.0f;
        s1p[(long long)t * st1] = s1a;
        m1p[(long long)t * st1] = m1;
        unsigned long long mka = __ballot(s1a != 0.0f);
        if (lane == 0) wmks[par][0][w] = mka;

        float rstb = (m1 > 1.0f) ? 1.0f : 0.0f;
        m1 = 0.9f * m1 + c1b - rstb;
        float s1b = (m1 > 1.0f) ? 1.0f : 0.0f;
        s1p[(long long)(t + 1) * st1] = s1b;
        m1p[(long long)(t + 1) * st1] = m1;
        unsigned long long mkb = __ballot(s1b != 0.0f);
        if (lane == 0) wmks[par][1][w] = mkb;

        barrier_lds();   // orders the wmks ds_writes only; stores stay in flight

        if (h < NO) {
            #pragma unroll
            for (int j = 0; j < 2; ++j) {
                int cnt = 0;
                #pragma unroll
                for (int i = 0; i < 8; ++i) cnt += __popcll(wmks[par][j][i] & w2m[i]);
                float c2 = 0.5f * (float)cnt;    // exact: multiples of 0.5
                float rst2 = (m2 > 1.0f) ? 1.0f : 0.0f;
                m2 = 0.8f * m2 + c2 - rst2;
                float s2 = (m2 > 1.0f) ? 1.0f : 0.0f;
                long long o2 = (long long)(t + j) * (BB * NO) + b * NO + h;
                out[C2_OFF + o2] = c2;
                out[S2_OFF + o2] = s2;
                out[M2_OFF + o2] = m2;
            }
        }
        c1a = c1c; c1b = c1d;
        // no trailing barrier: wmks double-buffered by iteration parity
    }
}

extern "C" void kernel_launch(void* const* d_in, const int* in_sizes, int n_in,
                              void* d_out, int out_size, void* d_ws, size_t ws_size,
                              hipStream_t stream) {
    const float* x  = (const float*)d_in[0];
    const float* W1 = (const float*)d_in[1];
    const float* W2 = (const float*)d_in[2];
    float* out = (float*)d_out;

    // scratch inside d_out: W image (512KB bf16) at start of spk1 region;
    // consumed by gemm1 before lif_kernel overwrites it (stream-ordered).
    short* Wp = (short*)(out + S1_OFF);
    float* C1 = out + C1_OFF;

    prep_w_kernel<<<(4 * 16 * 8 * 64 + 255) / 256, 256, 0, stream>>>(W1, Wp);
    gemm1_kernel<<<(TB / 128) * (GN / 128), 256, 0, stream>>>(x, Wp, C1);
    lif_kernel<<<BB, NH, 0, stream>>>(C1, W2, out);
}

// Round 12
// 263.171 us; speedup vs baseline: 1.1198x; 1.0943x over previous
//
#include <hip/hip_runtime.h>

// ---- problem constants ----
#define TT 100
#define BB 1024
#define NI 256
#define NH 512
#define NO 10
#define TB (TT*BB)            // 102400 rows
#define GK 512                 // doubled K (hi/lo interleave)
#define GN 512

// output layout (floats), return order: cur1, cur2, spk1, spk2, mem1, mem2
constexpr long long C1_OFF = 0;
constexpr long long C2_OFF = 52428800LL;            // + T*B*NH
constexpr long long S1_OFF = 53452800LL;            // + T*B*NO
constexpr long long S2_OFF = 105881600LL;
constexpr long long M1_OFF = 106905600LL;
constexpr long long M2_OFF = 159334400LL;

typedef short bf16x8 __attribute__((ext_vector_type(8)));
typedef float f32x4 __attribute__((ext_vector_type(4)));

// round-to-nearest-even f32 -> bf16 bits
__device__ __forceinline__ unsigned int rne_bf16(float f) {
    unsigned int u = __float_as_uint(f);
    return (u + 0x7fffu + ((u >> 16) & 1u)) >> 16;
}

// f32 -> packed [hi,lo] bf16 pair (Dekker split), bit-identical to prior rounds
__device__ __forceinline__ unsigned int pack_hilo(float f) {
    unsigned int hi = rne_bf16(f);
    float hif = __uint_as_float(hi << 16);
    float e = f - hif;
    unsigned int lo = rne_bf16(e);
    return (hi & 0xffffu) | (lo << 16);
}

__device__ __forceinline__ void pack4(uint4& d, const float4& a) {
    d.x = pack_hilo(a.x); d.y = pack_hilo(a.y); d.z = pack_hilo(a.z); d.w = pack_hilo(a.w);
}

// async global->LDS, 16B per lane; LDS dest = wave-uniform base + lane*16
__device__ __forceinline__ void gload16(const void* g, void* l) {
    __builtin_amdgcn_global_load_lds(
        (const __attribute__((address_space(1))) void*)g,
        (__attribute__((address_space(3))) void*)l, 16, 0, 0);
}

// ---- prep: W1 (f32 {0,0.5}) -> pre-swizzled LDS-image (R2/R7-proven) ----
__global__ void prep_w_kernel(const float* __restrict__ W1, short* __restrict__ Wimg) {
    int i = blockIdx.x * blockDim.x + threadIdx.x;
    if (i >= 4 * 16 * 128 * 4) return;
    int c16 = i & 3;
    int r   = (i >> 2) & 127;
    int kt  = (i >> 9) & 15;
    int p   = i >> 13;
    int usrc = c16 ^ ((r >> 1) & 3);
    int kbase = kt * 16 + usrc * 4;
    float4 w = *(const float4*)&W1[(long long)(p * 128 + r) * NI + kbase];
    float f[4] = {w.x, w.y, w.z, w.w};
    uint4 o;
    unsigned int* op = &o.x;
    #pragma unroll
    for (int j = 0; j < 4; ++j) {
        unsigned int hb = __float_as_uint(f[j]) >> 16;   // exact for 0 / 0.5
        op[j] = hb | (hb << 16);
    }
    ((uint4*)Wimg)[i] = o;
}

// ---- GEMM1 (byte-identical to R7's 260 µs version) ----
__launch_bounds__(256, 2)
__global__ void gemm1_kernel(const float* __restrict__ x, const short* __restrict__ Wimg,
                             float* __restrict__ C) {
    __shared__ short As[2][128][40];
    __shared__ short Ws[2][128][32];
    const int tid = threadIdx.x;
    const int bid = blockIdx.x;
    const int x8 = bid & 7;
    const int g  = bid >> 3;
    const int p  = g & 3;
    const int panel = (g >> 2) * 8 + x8;
    const int m0 = (799 - panel) * 128;    // reversed: high t written first
    const int n0 = p * 128;
    const int wid = tid >> 6;
    const int lane = tid & 63;
    const int wm = (wid >> 1) * 64;
    const int wn = (wid & 1) * 64;

    f32x4 acc[4][4] = {};

    const int srow = tid >> 2;
    const int sc4 = tid & 3;
    const long long ax0 = (long long)(m0 + srow) * NI + sc4 * 4;
    const long long ax1 = ax0 + 64LL * NI;

    const int fr = lane & 15;
    const int fk = (lane >> 4) * 8;
    const int swz = (((lane >> 4) ^ ((fr >> 1) & 3)) << 4);

    const short* wbase = Wimg + (long long)p * 16 * 4096;
    const int c0 = wid * 2;

    gload16(wbase + (c0    ) * 512 + lane * 8, (char*)&Ws[0][0][0] + (c0    ) * 1024);
    gload16(wbase + (c0 + 1) * 512 + lane * 8, (char*)&Ws[0][0][0] + (c0 + 1) * 1024);
    uint4 pa0, pa1;
    {
        float4 t0a = *(const float4*)&x[ax0];
        float4 t0b = *(const float4*)&x[ax1];
        uint4 q0, q1;
        pack4(q0, t0a); pack4(q1, t0b);
        *(uint4*)&As[0][srow][sc4 * 8]      = q0;
        *(uint4*)&As[0][srow + 64][sc4 * 8] = q1;
        float4 t1a = *(const float4*)&x[ax0 + 16];
        float4 t1b = *(const float4*)&x[ax1 + 16];
        pack4(pa0, t1a); pack4(pa1, t1b);
    }
    float4 raw0a = *(const float4*)&x[ax0 + 32];
    float4 raw0b = *(const float4*)&x[ax1 + 32];
    float4 raw1a = *(const float4*)&x[ax0 + 48];
    float4 raw1b = *(const float4*)&x[ax1 + 48];
    __syncthreads();

    #pragma unroll
    for (int kt = 0; kt < 16; ++kt) {
        const int cur = kt & 1;
        const int nxt = cur ^ 1;

        if (kt + 1 < 16) {
            const short* wt = wbase + (kt + 1) * 4096;
            gload16(wt + (c0    ) * 512 + lane * 8, (char*)&Ws[nxt][0][0] + (c0    ) * 1024);
            gload16(wt + (c0 + 1) * 512 + lane * 8, (char*)&Ws[nxt][0][0] + (c0 + 1) * 1024);
            *(uint4*)&As[nxt][srow][sc4 * 8]      = pa0;
            *(uint4*)&As[nxt][srow + 64][sc4 * 8] = pa1;
        }
        if (kt + 2 < 16) {
            if (cur == 0) { pack4(pa0, raw0a); pack4(pa1, raw0b); }
            else          { pack4(pa0, raw1a); pack4(pa1, raw1b); }
        }
        if (kt + 4 < 16) {
            if (cur == 0) {
                raw0a = *(const float4*)&x[ax0 + (long long)(kt + 4) * 16];
                raw0b = *(const float4*)&x[ax1 + (long long)(kt + 4) * 16];
            } else {
                raw1a = *(const float4*)&x[ax0 + (long long)(kt + 4) * 16];
                raw1b = *(const float4*)&x[ax1 + (long long)(kt + 4) * 16];
            }
        }

        bf16x8 af[4], wf[4];
        #pragma unroll
        for (int i = 0; i < 4; ++i) {
            af[i] = *(const bf16x8*)&As[cur][wm + i * 16 + fr][fk];
            wf[i] = *(const bf16x8*)((const char*)&Ws[cur][wn + i * 16 + fr][0] + swz);
        }
        #pragma unroll
        for (int i = 0; i < 4; ++i)
            #pragma unroll
            for (int j = 0; j < 4; ++j)
                acc[i][j] = __builtin_amdgcn_mfma_f32_16x16x32_bf16(af[i], wf[j], acc[i][j], 0, 0, 0);

        if (kt + 1 < 16) __syncthreads();
    }

    const int col = lane & 15;
    const int rbase = (lane >> 4) * 4;
    #pragma unroll
    for (int i = 0; i < 4; ++i) {
        #pragma unroll
        for (int j = 0; j < 4; ++j) {
            long long base = (long long)(m0 + wm + i * 16 + rbase) * GN + (n0 + wn + j * 16 + col);
            #pragma unroll
            for (int r = 0; r < 4; ++r)
                C[base + (long long)r * GN] = acc[i][j][r];
        }
    }
}

// ---- lif: barrier-free, LDS-free. One wave per b; lane owns h=lane*8..+7. ----
// Spike vector in-wave (8 bits/lane); GEMM2 via packed-u32 butterfly reduce
// (counts <= 512 -> no cross-half carry). All lanes run the 10 LIF2 chains
// redundantly; lanes 0-9 store c2/s2/m2 (one coalesced 40B store). Outputs
// bit-identical to R7's (same integers, same float ops, same addresses).
__launch_bounds__(256)
__global__ void lif_kernel(const float* __restrict__ cur1, const float* __restrict__ W2,
                           float* __restrict__ out) {
    const int tid = threadIdx.x;
    const int lane = tid & 63;
    const int b = blockIdx.x * 4 + (tid >> 6);   // 4 b per 256-thread block

    // per-lane W2 byte masks: bit j of w2b[o] = (W2[o][lane*8+j] != 0)
    unsigned int w2b[NO];
    #pragma unroll
    for (int o = 0; o < NO; ++o) {
        unsigned int m = 0;
        #pragma unroll
        for (int j = 0; j < 8; ++j)
            m |= (W2[o * NH + lane * 8 + j] != 0.0f) ? (1u << j) : 0u;
        w2b[o] = m;
    }

    const long long st1 = (long long)BB * NH;
    const long long idx = (long long)b * NH + lane * 8;
    const float* c1p = cur1 + idx;
    float* s1p = out + S1_OFF + idx;
    float* m1p = out + M1_OFF + idx;

    float m1[8] = {0.f, 0.f, 0.f, 0.f, 0.f, 0.f, 0.f, 0.f};
    float m2[NO];
    #pragma unroll
    for (int o = 0; o < NO; ++o) m2[o] = 0.f;

    // 2-t-deep register prefetch
    float4 a0 = *(const float4*)&c1p[0];
    float4 a1 = *(const float4*)&c1p[4];
    float4 b0 = *(const float4*)&c1p[st1];
    float4 b1 = *(const float4*)&c1p[st1 + 4];

    auto stepT = [&](int t, const float4& x0, const float4& x1) {
        const float cv[8] = {x0.x, x0.y, x0.z, x0.w, x1.x, x1.y, x1.z, x1.w};
        float s1v[8];
        unsigned int bits = 0;
        #pragma unroll
        for (int j = 0; j < 8; ++j) {
            float rst = (m1[j] > 1.0f) ? 1.0f : 0.0f;
            m1[j] = 0.9f * m1[j] + cv[j] - rst;
            float s = (m1[j] > 1.0f) ? 1.0f : 0.0f;
            s1v[j] = s;
            bits |= (s != 0.0f) ? (1u << j) : 0u;
        }
        float4 sq0 = {s1v[0], s1v[1], s1v[2], s1v[3]};
        float4 sq1 = {s1v[4], s1v[5], s1v[6], s1v[7]};
        float4 mq0 = {m1[0], m1[1], m1[2], m1[3]};
        float4 mq1 = {m1[4], m1[5], m1[6], m1[7]};
        *(float4*)&s1p[(long long)t * st1]     = sq0;
        *(float4*)&s1p[(long long)t * st1 + 4] = sq1;
        *(float4*)&m1p[(long long)t * st1]     = mq0;
        *(float4*)&m1p[(long long)t * st1 + 4] = mq1;

        // packed partial counts: pk[q] = count(2q) | count(2q+1)<<16
        unsigned int pk[5];
        #pragma unroll
        for (int q = 0; q < 5; ++q)
            pk[q] = (unsigned int)__popc(bits & w2b[2 * q])
                  | ((unsigned int)__popc(bits & w2b[2 * q + 1]) << 16);
        #pragma unroll
        for (int s = 1; s < 64; s <<= 1) {
            #pragma unroll
            for (int q = 0; q < 5; ++q)
                pk[q] += __shfl_xor(pk[q], s);
        }

        // LIF2 (all lanes redundantly); lanes 0-9 store their o
        float myc2 = 0.f, mys2 = 0.f, mym2 = 0.f;
        #pragma unroll
        for (int o = 0; o < NO; ++o) {
            unsigned int cnt = (o & 1) ? (pk[o >> 1] >> 16) : (pk[o >> 1] & 0xffffu);
            float c2 = 0.5f * (float)cnt;    // exact: multiples of 0.5
            float rst2 = (m2[o] > 1.0f) ? 1.0f : 0.0f;
            m2[o] = 0.8f * m2[o] + c2 - rst2;
            float s2 = (m2[o] > 1.0f) ? 1.0f : 0.0f;
            if (lane == o) { myc2 = c2; mys2 = s2; mym2 = m2[o]; }
        }
        if (lane < NO) {
            long long o2 = (long long)t * (BB * NO) + (long long)b * NO + lane;
            out[C2_OFF + o2] = myc2;
            out[S2_OFF + o2] = mys2;
            out[M2_OFF + o2] = mym2;
        }
    };

    for (int t = 0; t < TT; t += 2) {
        float4 na0 = {}, na1 = {}, nb0 = {}, nb1 = {};
        if (t + 2 < TT) {
            na0 = *(const float4*)&c1p[(long long)(t + 2) * st1];
            na1 = *(const float4*)&c1p[(long long)(t + 2) * st1 + 4];
            nb0 = *(const float4*)&c1p[(long long)(t + 3) * st1];
            nb1 = *(const float4*)&c1p[(long long)(t + 3) * st1 + 4];
        }
        stepT(t,     a0, a1);
        stepT(t + 1, b0, b1);
        a0 = na0; a1 = na1; b0 = nb0; b1 = nb1;
    }
}

extern "C" void kernel_launch(void* const* d_in, const int* in_sizes, int n_in,
                              void* d_out, int out_size, void* d_ws, size_t ws_size,
                              hipStream_t stream) {
    const float* x  = (const float*)d_in[0];
    const float* W1 = (const float*)d_in[1];
    const float* W2 = (const float*)d_in[2];
    float* out = (float*)d_out;

    // scratch inside d_out: W image (512KB bf16) at start of spk1 region;
    // consumed by gemm1 before lif_kernel overwrites it (stream-ordered).
    short* Wp = (short*)(out + S1_OFF);
    float* C1 = out + C1_OFF;

    {
        int units = NH * GK / 8;   // 32,768 16B-units
        prep_w_kernel<<<(units + 255) / 256, 256, 0, stream>>>(W1, Wp);
    }
    gemm1_kernel<<<(TB / 128) * (GN / 128), 256, 0, stream>>>(x, Wp, C1);
    lif_kernel<<<BB / 4, 256, 0, stream>>>(C1, W2, out);
}

// Round 13
// 262.226 us; speedup vs baseline: 1.1238x; 1.0036x over previous
//
#include <hip/hip_runtime.h>

// ---- problem constants ----
#define TT 100
#define BB 1024
#define NI 256
#define NH 512
#define NO 10
#define TB (TT*BB)            // 102400 rows
#define GK 512                 // doubled K (hi/lo interleave)
#define GN 512

// output layout (floats), return order: cur1, cur2, spk1, spk2, mem1, mem2
constexpr long long C1_OFF = 0;
constexpr long long C2_OFF = 52428800LL;            // + T*B*NH
constexpr long long S1_OFF = 53452800LL;            // + T*B*NO
constexpr long long S2_OFF = 105881600LL;
constexpr long long M1_OFF = 106905600LL;
constexpr long long M2_OFF = 159334400LL;

typedef short bf16x8 __attribute__((ext_vector_type(8)));
typedef float f32x4 __attribute__((ext_vector_type(4)));

// round-to-nearest-even f32 -> bf16 bits
__device__ __forceinline__ unsigned int rne_bf16(float f) {
    unsigned int u = __float_as_uint(f);
    return (u + 0x7fffu + ((u >> 16) & 1u)) >> 16;
}

// f32 -> packed [hi,lo] bf16 pair (Dekker split), bit-identical to prior rounds
__device__ __forceinline__ unsigned int pack_hilo(float f) {
    unsigned int hi = rne_bf16(f);
    float hif = __uint_as_float(hi << 16);
    float e = f - hif;
    unsigned int lo = rne_bf16(e);
    return (hi & 0xffffu) | (lo << 16);
}

__device__ __forceinline__ void pack4(uint4& d, const float4& a) {
    d.x = pack_hilo(a.x); d.y = pack_hilo(a.y); d.z = pack_hilo(a.z); d.w = pack_hilo(a.w);
}

// async global->LDS, 16B per lane; LDS dest = wave-uniform base + lane*16
__device__ __forceinline__ void gload16(const void* g, void* l) {
    __builtin_amdgcn_global_load_lds(
        (const __attribute__((address_space(1))) void*)g,
        (__attribute__((address_space(3))) void*)l, 16, 0, 0);
}

// LDS-only barrier (R5-proven correct): orders ds traffic without draining the
// global store stream (__syncthreads would emit s_waitcnt vmcnt(0)).
__device__ __forceinline__ void barrier_lds() {
    asm volatile("s_waitcnt lgkmcnt(0)" ::: "memory");
    __builtin_amdgcn_s_barrier();
}

// ---- prep: W1 (f32 {0,0.5}) -> pre-swizzled LDS-image (R2-proven) ----
__global__ void prep_w_kernel(const float* __restrict__ W1, short* __restrict__ Wimg) {
    int i = blockIdx.x * blockDim.x + threadIdx.x;
    if (i >= 4 * 16 * 128 * 4) return;
    int c16 = i & 3;
    int r   = (i >> 2) & 127;
    int kt  = (i >> 9) & 15;
    int p   = i >> 13;
    int usrc = c16 ^ ((r >> 1) & 3);
    int kbase = kt * 16 + usrc * 4;
    float4 w = *(const float4*)&W1[(long long)(p * 128 + r) * NI + kbase];
    float f[4] = {w.x, w.y, w.z, w.w};
    uint4 o;
    unsigned int* op = &o.x;
    #pragma unroll
    for (int j = 0; j < 4; ++j) {
        unsigned int hb = __float_as_uint(f[j]) >> 16;   // exact for 0 / 0.5
        op[j] = hb | (hb << 16);
    }
    ((uint4*)Wimg)[i] = o;
}

// ---- GEMM1 (R2-proven 128x128 structure; best measured) ----
__launch_bounds__(256, 2)
__global__ void gemm1_kernel(const float* __restrict__ x, const short* __restrict__ Wimg,
                             float* __restrict__ C) {
    __shared__ short As[2][128][40];
    __shared__ short Ws[2][128][32];
    const int tid = threadIdx.x;
    const int bid = blockIdx.x;
    const int x8 = bid & 7;
    const int g  = bid >> 3;
    const int p  = g & 3;
    const int panel = (g >> 2) * 8 + x8;
    const int m0 = (799 - panel) * 128;    // reversed: high t written first
    const int n0 = p * 128;
    const int wid = tid >> 6;
    const int lane = tid & 63;
    const int wm = (wid >> 1) * 64;
    const int wn = (wid & 1) * 64;

    f32x4 acc[4][4] = {};

    const int srow = tid >> 2;
    const int sc4 = tid & 3;
    const long long ax0 = (long long)(m0 + srow) * NI + sc4 * 4;
    const long long ax1 = ax0 + 64LL * NI;

    const int fr = lane & 15;
    const int fk = (lane >> 4) * 8;
    const int swz = (((lane >> 4) ^ ((fr >> 1) & 3)) << 4);

    const short* wbase = Wimg + (long long)p * 16 * 4096;
    const int c0 = wid * 2;

    gload16(wbase + (c0    ) * 512 + lane * 8, (char*)&Ws[0][0][0] + (c0    ) * 1024);
    gload16(wbase + (c0 + 1) * 512 + lane * 8, (char*)&Ws[0][0][0] + (c0 + 1) * 1024);
    uint4 pa0, pa1;
    {
        float4 t0a = *(const float4*)&x[ax0];
        float4 t0b = *(const float4*)&x[ax1];
        uint4 q0, q1;
        pack4(q0, t0a); pack4(q1, t0b);
        *(uint4*)&As[0][srow][sc4 * 8]      = q0;
        *(uint4*)&As[0][srow + 64][sc4 * 8] = q1;
        float4 t1a = *(const float4*)&x[ax0 + 16];
        float4 t1b = *(const float4*)&x[ax1 + 16];
        pack4(pa0, t1a); pack4(pa1, t1b);
    }
    float4 raw0a = *(const float4*)&x[ax0 + 32];
    float4 raw0b = *(const float4*)&x[ax1 + 32];
    float4 raw1a = *(const float4*)&x[ax0 + 48];
    float4 raw1b = *(const float4*)&x[ax1 + 48];
    __syncthreads();

    #pragma unroll
    for (int kt = 0; kt < 16; ++kt) {
        const int cur = kt & 1;
        const int nxt = cur ^ 1;

        if (kt + 1 < 16) {
            const short* wt = wbase + (kt + 1) * 4096;
            gload16(wt + (c0    ) * 512 + lane * 8, (char*)&Ws[nxt][0][0] + (c0    ) * 1024);
            gload16(wt + (c0 + 1) * 512 + lane * 8, (char*)&Ws[nxt][0][0] + (c0 + 1) * 1024);
            *(uint4*)&As[nxt][srow][sc4 * 8]      = pa0;
            *(uint4*)&As[nxt][srow + 64][sc4 * 8] = pa1;
        }
        if (kt + 2 < 16) {
            if (cur == 0) { pack4(pa0, raw0a); pack4(pa1, raw0b); }
            else          { pack4(pa0, raw1a); pack4(pa1, raw1b); }
        }
        if (kt + 4 < 16) {
            if (cur == 0) {
                raw0a = *(const float4*)&x[ax0 + (long long)(kt + 4) * 16];
                raw0b = *(const float4*)&x[ax1 + (long long)(kt + 4) * 16];
            } else {
                raw1a = *(const float4*)&x[ax0 + (long long)(kt + 4) * 16];
                raw1b = *(const float4*)&x[ax1 + (long long)(kt + 4) * 16];
            }
        }

        bf16x8 af[4], wf[4];
        #pragma unroll
        for (int i = 0; i < 4; ++i) {
            af[i] = *(const bf16x8*)&As[cur][wm + i * 16 + fr][fk];
            wf[i] = *(const bf16x8*)((const char*)&Ws[cur][wn + i * 16 + fr][0] + swz);
        }
        #pragma unroll
        for (int i = 0; i < 4; ++i)
            #pragma unroll
            for (int j = 0; j < 4; ++j)
                acc[i][j] = __builtin_amdgcn_mfma_f32_16x16x32_bf16(af[i], wf[j], acc[i][j], 0, 0, 0);

        if (kt + 1 < 16) __syncthreads();
    }

    const int col = lane & 15;
    const int rbase = (lane >> 4) * 4;
    #pragma unroll
    for (int i = 0; i < 4; ++i) {
        #pragma unroll
        for (int j = 0; j < 4; ++j) {
            long long base = (long long)(m0 + wm + i * 16 + rbase) * GN + (n0 + wn + j * 16 + col);
            #pragma unroll
            for (int r = 0; r < 4; ++r)
                C[base + (long long)r * GN] = acc[i][j][r];
        }
    }
}

// ---- fused LIF1 + GEMM2(popcount) + LIF2 (R7-proven best) ----
//   * t-unrolled x2: ONE barrier per 2 t
//   * barrier_lds(): no vmcnt(0) store-drain
//   * 2-deep c1 prefetch
__launch_bounds__(512)
__global__ void lif_kernel(const float* __restrict__ cur1, const float* __restrict__ W2,
                           float* __restrict__ out) {
    const int b = blockIdx.x;       // 0..1023
    const int h = threadIdx.x;      // 0..511
    const int w = h >> 6;
    const int lane = h & 63;

    __shared__ unsigned long long wmks[2][2][8];   // [iter parity][t parity][wave]
    __shared__ unsigned long long w2ms[NO][8];

    #pragma unroll
    for (int o = 0; o < NO; ++o) {
        unsigned long long mk = __ballot(W2[o * NH + h] != 0.0f);
        if (lane == 0) w2ms[o][w] = mk;
    }
    __syncthreads();
    unsigned long long w2m[8];
    if (h < NO) {
        #pragma unroll
        for (int i = 0; i < 8; ++i) w2m[i] = w2ms[h][i];
    }

    float m1 = 0.0f, m2 = 0.0f;
    const long long idx1 = (long long)b * NH + h;
    const float* c1p = cur1 + idx1;
    float* s1p = out + S1_OFF + idx1;
    float* m1p = out + M1_OFF + idx1;
    const long long st1 = (long long)BB * NH;   // per-t stride

    float c1a = c1p[0];
    float c1b = c1p[st1];
    for (int t = 0; t < TT; t += 2) {
        const int par = (t >> 1) & 1;

        float c1c = 0.0f, c1d = 0.0f;
        if (t + 2 < TT) c1c = c1p[(long long)(t + 2) * st1];
        if (t + 3 < TT) c1d = c1p[(long long)(t + 3) * st1];

        float rst = (m1 > 1.0f) ? 1.0f : 0.0f;
        m1 = 0.9f * m1 + c1a - rst;
        float s1a = (m1 > 1.0f) ? 1.0f : 0.0f;
        s1p[(long long)t * st1] = s1a;
        m1p[(long long)t * st1] = m1;
        unsigned long long mka = __ballot(s1a != 0.0f);
        if (lane == 0) wmks[par][0][w] = mka;

        float rstb = (m1 > 1.0f) ? 1.0f : 0.0f;
        m1 = 0.9f * m1 + c1b - rstb;
        float s1b = (m1 > 1.0f) ? 1.0f : 0.0f;
        s1p[(long long)(t + 1) * st1] = s1b;
        m1p[(long long)(t + 1) * st1] = m1;
        unsigned long long mkb = __ballot(s1b != 0.0f);
        if (lane == 0) wmks[par][1][w] = mkb;

        barrier_lds();   // orders the wmks ds_writes only; stores stay in flight

        if (h < NO) {
            #pragma unroll
            for (int j = 0; j < 2; ++j) {
                int cnt = 0;
                #pragma unroll
                for (int i = 0; i < 8; ++i) cnt += __popcll(wmks[par][j][i] & w2m[i]);
                float c2 = 0.5f * (float)cnt;    // exact: multiples of 0.5
                float rst2 = (m2 > 1.0f) ? 1.0f : 0.0f;
                m2 = 0.8f * m2 + c2 - rst2;
                float s2 = (m2 > 1.0f) ? 1.0f : 0.0f;
                long long o2 = (long long)(t + j) * (BB * NO) + b * NO + h;
                out[C2_OFF + o2] = c2;
                out[S2_OFF + o2] = s2;
                out[M2_OFF + o2] = m2;
            }
        }
        c1a = c1c; c1b = c1d;
        // no trailing barrier: wmks double-buffered by iteration parity
    }
}

extern "C" void kernel_launch(void* const* d_in, const int* in_sizes, int n_in,
                              void* d_out, int out_size, void* d_ws, size_t ws_size,
                              hipStream_t stream) {
    const float* x  = (const float*)d_in[0];
    const float* W1 = (const float*)d_in[1];
    const float* W2 = (const float*)d_in[2];
    float* out = (float*)d_out;

    // scratch inside d_out: W image (512KB bf16) at start of spk1 region;
    // consumed by gemm1 before lif_kernel overwrites it (stream-ordered).
    short* Wp = (short*)(out + S1_OFF);
    float* C1 = out + C1_OFF;

    {
        int units = NH * GK / 8;   // 32,768 16B-units
        prep_w_kernel<<<(units + 255) / 256, 256, 0, stream>>>(W1, Wp);
    }
    gemm1_kernel<<<(TB / 128) * (GN / 128), 256, 0, stream>>>(x, Wp, C1);
    lif_kernel<<<BB, NH, 0, stream>>>(C1, W2, out);
}